// Round 7
// baseline (297.765 us; speedup 1.0000x reference)
//
#include <hip/hip_runtime.h>

// x (B=64, C=256, T=2048) fp32; conv_weight (256,256,3); beta (1,); b (256,).
// Output spikes (B,C,T) fp32 in {0,1}.
//
// Established: R5: 128-step speculative warmup bit-exact. R6 (92.6us)
// blocking fill. R7-R10: register pipelining compiler-defeated. R11 (94.7us)
// real async DMA pipeline, 1-deep -- flat. R12 (92.8us) whole-row tile,
// true 1KB-contiguous requests, -14% bytes (FETCH 94->65.6 MB) -- FLAT.
// Three structurally different kernels pinned at ~93us. Copy ubench = one
// 1KB instr per ~100cyc/CU; ours ~175-218. Difference is DUTY CYCLE: copy
// waves issue vmem continuously (permanent MLP); ours issue short bursts
// separated by long quiet compute/drain. Time-avg outstanding bytes/CU is
// far below the ~15KB Little's-law need for 6TB/s.
// R13: maximize SUSTAINED MLP at constant instr count. SEGS=8/WARM=128
// shell (proven), PW=16 (fine phases, short gaps), depth-3 ring of 4 x 4KB
// buffers (12KB permanently in flight per wave), 16.4KB LDS -> all 8 grid
// waves/CU resident. Exact vmcnt ladder (12/16/20/24 steady; 20/16/12 tail).
// Instr count = 1280/CU == R6/R11: result cleanly discriminates MLP theory
// (gain) vs per-instr serialization law (flat -> structural ceiling).
#define C_DIM 256
#define T_DIM 2048
#define B_DIM 64
#define NROWS (B_DIM * C_DIM)          // 16384
#define SEGS 8
#define SEGL (T_DIM / SEGS)            // 256 emitted timesteps per segment
#define WARM 128                       // speculative warmup steps (bit-exact, r5)
#define PW   16                        // phase window: floats per stream per phase
#define NPH  ((WARM + SEGL) / PW)      // 24 phases
#define WARM_PH (WARM / PW)            // 8 warmup phases
#define NSTR 64                        // streams per block (= wave size)
#define NBUF 4                         // ring buffers (depth-3 prefetch)
#define BUF_F (NSTR * PW)              // 1024 floats = 4 KB per buffer

__device__ __forceinline__ float sqrn(float v) { return __fmul_rn(v, v); }

// norm[c] = sum of squares of 768 floats in numpy's exact pairwise order
// (768->384->192->96; 96-blocks via 8-accumulator unrolled loop).
// Verified bit-exact (rounds 1-12 absmax 0). DO NOT change the summation tree.
__global__ __launch_bounds__(64) void norm_kernel(const float* __restrict__ w,
                                                  const float* __restrict__ b,
                                                  float* __restrict__ bn,
                                                  float* __restrict__ ninv) {
    const int c = blockIdx.x;
    const int k = threadIdx.x;
    __shared__ float q[8];
    if (k < 8) {
        const float* a = w + c * 768 + k * 96;
        float r0 = sqrn(a[0]), r1 = sqrn(a[1]), r2 = sqrn(a[2]), r3 = sqrn(a[3]);
        float r4 = sqrn(a[4]), r5 = sqrn(a[5]), r6 = sqrn(a[6]), r7 = sqrn(a[7]);
        #pragma unroll
        for (int i = 8; i < 96; i += 8) {
            r0 = __fadd_rn(r0, sqrn(a[i + 0]));
            r1 = __fadd_rn(r1, sqrn(a[i + 1]));
            r2 = __fadd_rn(r2, sqrn(a[i + 2]));
            r3 = __fadd_rn(r3, sqrn(a[i + 3]));
            r4 = __fadd_rn(r4, sqrn(a[i + 4]));
            r5 = __fadd_rn(r5, sqrn(a[i + 5]));
            r6 = __fadd_rn(r6, sqrn(a[i + 6]));
            r7 = __fadd_rn(r7, sqrn(a[i + 7]));
        }
        q[k] = __fadd_rn(__fadd_rn(__fadd_rn(r0, r1), __fadd_rn(r2, r3)),
                         __fadd_rn(__fadd_rn(r4, r5), __fadd_rn(r6, r7)));
    }
    __syncthreads();
    if (k == 0) {
        float s = __fadd_rn(__fadd_rn(__fadd_rn(q[0], q[1]), __fadd_rn(q[2], q[3])),
                            __fadd_rn(__fadd_rn(q[4], q[5]), __fadd_rn(q[6], q[7])));
        bn[c]   = __fmul_rn(b[c], s);
        ninv[c] = 1.0f / __fadd_rn(s, 1e-8f);
    }
}

// One LIF step, bit-exact vs numpy semantics (verified absmax 0, rounds 4-12):
// speculative dual-path update + sign-bit select, no VCC.
__device__ __forceinline__ float step_fast(float xw, float& mem, int& mask,
                                           float bnc, float beta, float nic, float bc) {
    float m0 = __fmul_rn(mem, beta);
    float m1 = __fmul_rn(__fsub_rn(mem, bnc), beta);
    m0 = __fadd_rn(m0, xw);
    m1 = __fadd_rn(m1, xw);
    int mi = (__float_as_int(m1) & mask) | (__float_as_int(m0) & ~mask);
    mem = __int_as_float(mi);
    float p = __fmul_rn(mem, nic);
    float d = __fsub_rn(bc, p);
    mask = __float_as_int(d) >> 31;                 // -1 if spike else 0
    return __int_as_float(mask & 0x3f800000);       // 1.0f or 0.0f
}

#define STEP4_NOSTORE(v)                                                   \
    do {                                                                   \
        float xw0 = __fmul_rn((v).x, omb);                                 \
        float xw1 = __fmul_rn((v).y, omb);                                 \
        float xw2 = __fmul_rn((v).z, omb);                                 \
        float xw3 = __fmul_rn((v).w, omb);                                 \
        (void)step_fast(xw0, mem, mask, bnc, beta, nic, bc);               \
        (void)step_fast(xw1, mem, mask, bnc, beta, nic, bc);               \
        (void)step_fast(xw2, mem, mask, bnc, beta, nic, bc);               \
        (void)step_fast(xw3, mem, mask, bnc, beta, nic, bc);               \
    } while (0)

#define STEP4_STORE(v, o)                                                  \
    do {                                                                   \
        float xw0 = __fmul_rn((v).x, omb);                                 \
        float xw1 = __fmul_rn((v).y, omb);                                 \
        float xw2 = __fmul_rn((v).z, omb);                                 \
        float xw3 = __fmul_rn((v).w, omb);                                 \
        (o).x = step_fast(xw0, mem, mask, bnc, beta, nic, bc);             \
        (o).y = step_fast(xw1, mem, mask, bnc, beta, nic, bc);             \
        (o).z = step_fast(xw2, mem, mask, bnc, beta, nic, bc);             \
        (o).w = step_fast(xw3, mem, mask, bnc, beta, nic, bc);             \
    } while (0)

// lgkm-only wait: cross-lane LDS handoff within a wave (proven in r2).
#define WAITCNT_LGKM0  0xC07F
#define WAITVM(n)  asm volatile("s_waitcnt vmcnt(" #n ")" ::: "memory")

// Async global -> LDS, 16B per lane. LDS dest = wave-uniform base + lane*16.
__device__ __forceinline__ void dma16(const float* gp, float* lp) {
    __builtin_amdgcn_global_load_lds(
        (const __attribute__((address_space(1))) void*)gp,
        (__attribute__((address_space(3))) void*)lp,
        16, 0, 0);
}

// Block = 1 wave = 64 streams (8 rows x 8 segs). 2048 blocks = 8 waves/CU,
// all resident (16.4KB LDS). Stream s: row = blk*8 + (s>>3), seg = s&7,
// local steps [0,384) = t in [seg*256-128, seg*256+256). 24 phases of 16
// steps: P 0..7 warmup (seg 0 clamped reads then state reset -- proven),
// P 8..23 emit.
//
// LDS ring: buf[4][64 streams][16 floats], XOR-swizzled at float4-unit
// granularity: logical unit u = 4*stream + chunk lives at phys u^((u>>3)&7)
// (involution; spreads every access pattern 8 lanes/bank-quad). DMA writes
// phys-linear, so the GLOBAL source is pre-swizzled (rule #21).
// Per phase P: issue 4 DMAs for batch P+3 (buf[(P+3)&3]) -> exact-count
// vmcnt wait for batch P -> 16 steps from buf[P&3] -> [emit: writeback,
// lgkm, 4 drain stores]. 12KB (3 batches) permanently in flight per wave;
// phase gaps are ~400cyc, so issue is near-continuous.
__global__ __launch_bounds__(64)
void lif_seg_kernel(const float* __restrict__ x,
                    const float* __restrict__ beta_p,
                    const float* __restrict__ b,
                    const float* __restrict__ bn,
                    const float* __restrict__ ninv,
                    float* __restrict__ out) {
    __shared__ __align__(16) float lds[NBUF * BUF_F];   // 16 KB

    const int lane = threadIdx.x;        // = my stream index within block
    const int seg  = lane & 7;
    const size_t row = (size_t)blockIdx.x * 8 + (lane >> 3);
    const int c    = (int)(row & (C_DIM - 1));

    const float beta = beta_p[0];
    const float omb  = __fsub_rn(1.0f, beta);
    const float bnc  = bn[c];
    const float nic  = ninv[c];
    const float bc   = b[c];

    float mem = 0.0f;
    int   mask = 0;

    // fill/drain lane->logical mapping for vmem instr j (phys unit p=64j+lane):
    // l = p ^ ((p>>3)&7); stream sl = l>>2, chunk g = l&3.
    // Precompute per-j constants (j = 0..3): p depends on lane only via +64j.

    // ---- prologue: issue DMA batches 0,1,2 (12 DMAs, 12 KB in flight) ----
    #pragma unroll
    for (int bq = 0; bq < 3; ++bq) {
        float* dst = lds + bq * BUF_F;
        #pragma unroll
        for (int j = 0; j < 4; ++j) {
            const int p  = 64 * j + lane;
            const int l  = p ^ ((p >> 3) & 7);
            const int sl = l >> 2, g = l & 3;
            const size_t srow = (size_t)blockIdx.x * 8 + (sl >> 3);
            int r = (sl & 7) * SEGL - WARM + bq * PW;
            if (r < 0) r = 0;                        // clamped warmup (discarded)
            dma16(x + srow * T_DIM + r + 4 * g, dst + j * 256);
        }
    }

    #pragma unroll 1
    for (int P = 0; P < NPH; ++P) {
        // ---- issue DMA batch P+3 ----
        if (P + 3 < NPH) {
            float* dst = lds + ((P + 3) & 3) * BUF_F;
            #pragma unroll
            for (int j = 0; j < 4; ++j) {
                const int p  = 64 * j + lane;
                const int l  = p ^ ((p >> 3) & 7);
                const int sl = l >> 2, g = l & 3;
                const size_t srow = (size_t)blockIdx.x * 8 + (sl >> 3);
                int r = (sl & 7) * SEGL - WARM + (P + 3) * PW;
                if (r < 0) r = 0;                    // clamped warmup (discarded)
                dma16(x + srow * T_DIM + r + 4 * g, dst + j * 256);
            }
        }

        // ---- exact vmcnt ladder: wait for batch P only ----
        // newer-in-flight = 4*(#newer DMA batches) + 4*(#emit stores in last
        // 3 phases). Steady emit = 24; ramps 12/16/20; tail 20/16/12.
        if      (P <= WARM_PH)     { WAITVM(12); }
        else if (P == WARM_PH + 1) { WAITVM(16); }
        else if (P == WARM_PH + 2) { WAITVM(20); }
        else if (P <= NPH - 4)     { WAITVM(24); }
        else if (P == NPH - 3)     { WAITVM(20); }
        else if (P == NPH - 2)     { WAITVM(16); }
        else                       { WAITVM(12); }

        float* mybuf = lds + (P & 3) * BUF_F;

        if (P < WARM_PH) {
            // ---- warmup: 16 steps, no output ----
            #pragma unroll
            for (int G = 0; G < PW / 4; ++G) {
                const int u  = 4 * lane + G;
                const int ph = u ^ ((u >> 3) & 7);
                float4 v = *(const float4*)(mybuf + 4 * ph);
                STEP4_NOSTORE(v);
            }
            if (P == WARM_PH - 1) {
                // seg 0 has no predecessor: restore the true initial state.
                if (seg == 0) { mem = 0.0f; mask = 0; }
            }
        } else {
            // ---- emit: 16 steps, spikes written back in place ----
            #pragma unroll
            for (int G = 0; G < PW / 4; ++G) {
                const int u  = 4 * lane + G;
                const int ph = u ^ ((u >> 3) & 7);
                float* a = mybuf + 4 * ph;
                float4 v = *(const float4*)a;
                float4 o;
                STEP4_STORE(v, o);
                *(float4*)a = o;
            }
            __builtin_amdgcn_s_waitcnt(WAITCNT_LGKM0);   // spikes visible to drain lanes

            // ---- drain: 4 coalesced-phys LDS reads -> pre-swizzled stores ----
            #pragma unroll
            for (int j = 0; j < 4; ++j) {
                const int p  = 64 * j + lane;
                const int l  = p ^ ((p >> 3) & 7);
                const int sl = l >> 2, g = l & 3;
                const size_t srow = (size_t)blockIdx.x * 8 + (sl >> 3);
                const int r = (sl & 7) * SEGL - WARM + P * PW;   // >= 0 for P >= 8
                float4 v = *(const float4*)(mybuf + 4 * p);
                *(float4*)(out + srow * T_DIM + r + 4 * g) = v;
            }
        }
    }
}

extern "C" void kernel_launch(void* const* d_in, const int* in_sizes, int n_in,
                              void* d_out, int out_size, void* d_ws, size_t ws_size,
                              hipStream_t stream) {
    const float* x    = (const float*)d_in[0];
    const float* w    = (const float*)d_in[1];
    const float* beta = (const float*)d_in[2];
    const float* b    = (const float*)d_in[3];
    float* out  = (float*)d_out;
    float* bn   = (float*)d_ws;          // 256 floats
    float* ninv = bn + C_DIM;            // 256 floats

    norm_kernel<<<C_DIM, 64, 0, stream>>>(w, b, bn, ninv);
    lif_seg_kernel<<<(NROWS * SEGS) / NSTR, NSTR, 0, stream>>>(x, beta, b, bn, ninv, out);
}

// Round 8
// 254.585 us; speedup vs baseline: 1.1696x; 1.1696x over previous
//
#include <hip/hip_runtime.h>

// x (B=64, C=256, T=2048) fp32; conv_weight (256,256,3); beta (1,); b (256,).
// Output spikes (B,C,T) fp32 in {0,1}.
//
// History: R5 proved 128-step speculative warmup bit-exact. R6 92.6us
// (blocking fill); R7-R10 register pipelining compiler-defeated; R11 94.7us
// (true async DMA ring + swizzle); R12 92.8us (contiguous 1KB, -19% bytes);
// R13 118us (3-deep ring, 16B-scattered stores -> +28MB write amplification).
// Conclusion: time is insensitive to schedule, bytes, contiguity, occupancy
// within the fused read+write shape (~3.5 TB/s requested ceiling).
// R14: SPLIT THE STREAMS. k1 = R11 shell, byte-identical arithmetic, but
// emits spikes as packed bits (u32 per 32 steps per stream): writes 131->4 MB,
// store instrs 64->8/wave; k1 is now ~pure-read (192 MB requested).
// k2 = bit->fp32 expand with perfectly coalesced 1KB stores (135 MB,
// copy-class). If k1 alone still takes ~90us, the read path is the wall and
// that is the structural floor (discriminator). Fallback: if ws_size < 4MB+4K
// the proven R11 single-kernel runs instead (bit-identical output).
#define C_DIM 256
#define T_DIM 2048
#define B_DIM 64
#define NROWS (B_DIM * C_DIM)          // 16384
#define SEGS 8
#define SEGL (T_DIM / SEGS)            // 256 emitted timesteps per segment
#define WARM 128                       // speculative warmup steps (bit-exact, r5)
#define PW   32                        // phase window: floats per stream per phase
#define NPH  ((WARM + SEGL) / PW)      // 12 phases
#define WARM_PH (WARM / PW)            // 4 warmup phases
#define NSTR 64                        // streams per block (= wave size)
#define BUF_F (NSTR * PW)              // 2048 floats = 8 KB per buffer
#define NSTREAMS (NROWS * SEGS)        // 131072 total streams
#define PK_BYTES (NSTREAMS * (SEGL / 32) * 4)   // 4 MB packed spikes

__device__ __forceinline__ float sqrn(float v) { return __fmul_rn(v, v); }

// norm[c] = sum of squares of 768 floats in numpy's exact pairwise order
// (768->384->192->96; 96-blocks via 8-accumulator unrolled loop).
// Verified bit-exact (rounds 1-13 absmax 0). DO NOT change the summation tree.
__global__ __launch_bounds__(64) void norm_kernel(const float* __restrict__ w,
                                                  const float* __restrict__ b,
                                                  float* __restrict__ bn,
                                                  float* __restrict__ ninv) {
    const int c = blockIdx.x;
    const int k = threadIdx.x;
    __shared__ float q[8];
    if (k < 8) {
        const float* a = w + c * 768 + k * 96;
        float r0 = sqrn(a[0]), r1 = sqrn(a[1]), r2 = sqrn(a[2]), r3 = sqrn(a[3]);
        float r4 = sqrn(a[4]), r5 = sqrn(a[5]), r6 = sqrn(a[6]), r7 = sqrn(a[7]);
        #pragma unroll
        for (int i = 8; i < 96; i += 8) {
            r0 = __fadd_rn(r0, sqrn(a[i + 0]));
            r1 = __fadd_rn(r1, sqrn(a[i + 1]));
            r2 = __fadd_rn(r2, sqrn(a[i + 2]));
            r3 = __fadd_rn(r3, sqrn(a[i + 3]));
            r4 = __fadd_rn(r4, sqrn(a[i + 4]));
            r5 = __fadd_rn(r5, sqrn(a[i + 5]));
            r6 = __fadd_rn(r6, sqrn(a[i + 6]));
            r7 = __fadd_rn(r7, sqrn(a[i + 7]));
        }
        q[k] = __fadd_rn(__fadd_rn(__fadd_rn(r0, r1), __fadd_rn(r2, r3)),
                         __fadd_rn(__fadd_rn(r4, r5), __fadd_rn(r6, r7)));
    }
    __syncthreads();
    if (k == 0) {
        float s = __fadd_rn(__fadd_rn(__fadd_rn(q[0], q[1]), __fadd_rn(q[2], q[3])),
                            __fadd_rn(__fadd_rn(q[4], q[5]), __fadd_rn(q[6], q[7])));
        bn[c]   = __fmul_rn(b[c], s);
        ninv[c] = 1.0f / __fadd_rn(s, 1e-8f);
    }
}

// One LIF step, bit-exact vs numpy semantics (verified absmax 0, rounds 4-13):
// speculative dual-path update + sign-bit select, no VCC.
__device__ __forceinline__ float step_fast(float xw, float& mem, int& mask,
                                           float bnc, float beta, float nic, float bc) {
    float m0 = __fmul_rn(mem, beta);
    float m1 = __fmul_rn(__fsub_rn(mem, bnc), beta);
    m0 = __fadd_rn(m0, xw);
    m1 = __fadd_rn(m1, xw);
    int mi = (__float_as_int(m1) & mask) | (__float_as_int(m0) & ~mask);
    mem = __int_as_float(mi);
    float p = __fmul_rn(mem, nic);
    float d = __fsub_rn(bc, p);
    mask = __float_as_int(d) >> 31;                 // -1 if spike else 0
    return __int_as_float(mask & 0x3f800000);       // 1.0f or 0.0f
}

#define STEP4_NOSTORE(v)                                                   \
    do {                                                                   \
        float xw0 = __fmul_rn((v).x, omb);                                 \
        float xw1 = __fmul_rn((v).y, omb);                                 \
        float xw2 = __fmul_rn((v).z, omb);                                 \
        float xw3 = __fmul_rn((v).w, omb);                                 \
        (void)step_fast(xw0, mem, mask, bnc, beta, nic, bc);               \
        (void)step_fast(xw1, mem, mask, bnc, beta, nic, bc);               \
        (void)step_fast(xw2, mem, mask, bnc, beta, nic, bc);               \
        (void)step_fast(xw3, mem, mask, bnc, beta, nic, bc);               \
    } while (0)

// 4 steps, packing the 4 spike bits into `word` at bit base bp (compile-time
// per unroll iteration). Bit value = mask&1 after each step (mask is -1/0).
#define STEP4_PACK(v, bp)                                                  \
    do {                                                                   \
        float xw0 = __fmul_rn((v).x, omb);                                 \
        float xw1 = __fmul_rn((v).y, omb);                                 \
        float xw2 = __fmul_rn((v).z, omb);                                 \
        float xw3 = __fmul_rn((v).w, omb);                                 \
        (void)step_fast(xw0, mem, mask, bnc, beta, nic, bc);               \
        word |= (unsigned)mask & (1u << ((bp) + 0));                       \
        (void)step_fast(xw1, mem, mask, bnc, beta, nic, bc);               \
        word |= (unsigned)mask & (1u << ((bp) + 1));                       \
        (void)step_fast(xw2, mem, mask, bnc, beta, nic, bc);               \
        word |= (unsigned)mask & (1u << ((bp) + 2));                       \
        (void)step_fast(xw3, mem, mask, bnc, beta, nic, bc);               \
        word |= (unsigned)mask & (1u << ((bp) + 3));                       \
    } while (0)

#define STEP4_STORE(v, o)                                                  \
    do {                                                                   \
        float xw0 = __fmul_rn((v).x, omb);                                 \
        float xw1 = __fmul_rn((v).y, omb);                                 \
        float xw2 = __fmul_rn((v).z, omb);                                 \
        float xw3 = __fmul_rn((v).w, omb);                                 \
        (o).x = step_fast(xw0, mem, mask, bnc, beta, nic, bc);             \
        (o).y = step_fast(xw1, mem, mask, bnc, beta, nic, bc);             \
        (o).z = step_fast(xw2, mem, mask, bnc, beta, nic, bc);             \
        (o).w = step_fast(xw3, mem, mask, bnc, beta, nic, bc);             \
    } while (0)

// lgkm-only wait: cross-lane LDS handoff within a wave (proven in r2).
#define WAITCNT_LGKM0  0xC07F
#define WAITVM(n)  asm volatile("s_waitcnt vmcnt(" #n ")" ::: "memory")

// Async global -> LDS, 16B per lane. LDS dest = wave-uniform base + lane*16.
__device__ __forceinline__ void dma16(const float* gp, float* lp) {
    __builtin_amdgcn_global_load_lds(
        (const __attribute__((address_space(1))) void*)gp,
        (__attribute__((address_space(3))) void*)lp,
        16, 0, 0);
}

// ============================ k1: LIF + bitpack =============================
// R11 shell verbatim (proven absmax 0): block = 1 wave = 64 streams (8 rows x
// 8 segs), 2048 blocks = 8 waves/CU, LDS dbuf 2x8KB, XOR swizzle
// phys_unit = logical_unit ^ (stream&7) via pre-swizzled global DMA source.
// Emit phases P=4..11: each covers exactly one u32 word (32 steps); spikes
// accumulate in `word` and are stored once per phase, coalesced:
// pk[(P-4)*NSTREAMS + blk*64 + lane] (gid = row*8+seg = blk*64+lane).
// No LDS writeback, no drain: per-wave vmem = 96 DMA + 8 stores.
__global__ __launch_bounds__(64)
void lif_pack_kernel(const float* __restrict__ x,
                     const float* __restrict__ beta_p,
                     const float* __restrict__ b,
                     const float* __restrict__ bn,
                     const float* __restrict__ ninv,
                     unsigned* __restrict__ pk) {
    __shared__ __align__(16) float lds[2 * BUF_F];   // 16 KB

    const int lane = threadIdx.x;        // = my stream index within block
    const int seg  = lane & 7;
    const size_t row = (size_t)blockIdx.x * 8 + (lane >> 3);
    const int c    = (int)(row & (C_DIM - 1));
    const int lk   = lane & 7;           // XOR key for my compute row

    const int ds  = lane >> 3;           // fill role: segment
    const int du  = lane & 7;            // fill role: float4 unit
    const int swz = du ^ ds;             // pre-swizzled unit

    const float beta = beta_p[0];
    const float omb  = __fsub_rn(1.0f, beta);
    const float bnc  = bn[c];
    const float nic  = ninv[c];
    const float bc   = b[c];

    float mem = 0.0f;
    int   mask = 0;

    // ---- prologue: DMA phase 0 into buf 0 ----
    {
        int rel = ds * SEGL - WARM;                  // P = 0
        if (rel < 0) rel = 0;                        // clamped warmup (discarded)
        const float* g = x + rel + 4 * swz;
        #pragma unroll
        for (int q = 0; q < 8; ++q) {
            const size_t grow = (size_t)(blockIdx.x * 8 + q);
            dma16(g + grow * T_DIM, lds + q * (8 * PW));
        }
    }

    #pragma unroll 1
    for (int P = 0; P < NPH; ++P) {
        const int cur = P & 1;
        float* buf = lds + cur * BUF_F;

        // ---- issue DMA for phase P+1 into the other buffer ----
        if (P + 1 < NPH) {
            int rel = ds * SEGL - WARM + (P + 1) * PW;   // <0 only seg 0, P+1<4
            if (rel < 0) rel = 0;
            const float* g = x + rel + 4 * swz;
            float* dst = lds + (cur ^ 1) * BUF_F;
            #pragma unroll
            for (int q = 0; q < 8; ++q) {
                const size_t grow = (size_t)(blockIdx.x * 8 + q);
                dma16(g + grow * T_DIM, dst + q * (8 * PW));
            }
        }

        // ---- wait for buf[cur]'s DMA batch (issued one phase ago) ----
        // outstanding newer = 8 just-issued DMAs (+ <=1 quick pk store).
        if (P + 1 < NPH) { WAITVM(8); } else { WAITVM(0); }

        float* my = buf + lane * PW;

        if (P < WARM_PH) {
            // ---- warmup phase: 32 steps, no output ----
            #pragma unroll
            for (int g = 0; g < PW / 4; ++g) {
                float4 v = *(const float4*)(my + 4 * (g ^ lk));
                STEP4_NOSTORE(v);
            }
            if (P == WARM_PH - 1) {
                // seg 0 has no predecessor: restore the true initial state.
                if (seg == 0) { mem = 0.0f; mask = 0; }
            }
        } else {
            // ---- emit phase: 32 steps -> one packed u32, one coalesced store ----
            unsigned word = 0u;
            #pragma unroll
            for (int g = 0; g < PW / 4; ++g) {
                float4 v = *(const float4*)(my + 4 * (g ^ lk));
                STEP4_PACK(v, 4 * g);
            }
            pk[(size_t)(P - WARM_PH) * NSTREAMS + (size_t)blockIdx.x * 64 + lane] = word;
        }
    }
}

// ============================ k2: bit -> fp32 expand ========================
// Wave handles 8 rows. Per row: lane j loads word (w=j>>3, seg=j&7) of the
// row (8x32B chunks); for output group i (i=0..7) lane j writes float4 at
// row*2048 + 4*(64i+j) (1KB fully coalesced per instr) using word
// (seg=i, w=j>>3) pulled via shfl from lane (j&56)|i; its 4 bits sit at
// bit offset 4*(j&7). Float = ((int)(wv << (31-bp)) >> 31) & 0x3f800000.
__global__ __launch_bounds__(64)
void expand_kernel(const unsigned* __restrict__ pk, float* __restrict__ out) {
    const int lane = threadIdx.x;
    const int shl0 = 31 - 4 * (lane & 7);          // shift to put bit bp at sign
    #pragma unroll 1
    for (int q = 0; q < 8; ++q) {
        const size_t row = (size_t)blockIdx.x * 8 + q;
        // my word: w = lane>>3, seg = lane&7 -> pk[w*NSTREAMS + row*8 + seg]
        const unsigned mine =
            pk[(size_t)(lane >> 3) * NSTREAMS + row * 8 + (lane & 7)];
        float* orow = out + row * T_DIM;
        #pragma unroll
        for (int i = 0; i < 8; ++i) {
            const unsigned wv = (unsigned)__shfl((int)mine, (lane & 56) | i, 64);
            float4 o;
            o.x = __int_as_float(((int)(wv << (shl0 - 0)) >> 31) & 0x3f800000);
            o.y = __int_as_float(((int)(wv << (shl0 - 1)) >> 31) & 0x3f800000);
            o.z = __int_as_float(((int)(wv << (shl0 - 2)) >> 31) & 0x3f800000);
            o.w = __int_as_float(((int)(wv << (shl0 - 3)) >> 31) & 0x3f800000);
            *(float4*)(orow + 4 * (64 * i + lane)) = o;
        }
    }
}

// ==================== fallback: proven R11 single kernel ====================
__global__ __launch_bounds__(64)
void lif_seg_kernel(const float* __restrict__ x,
                    const float* __restrict__ beta_p,
                    const float* __restrict__ b,
                    const float* __restrict__ bn,
                    const float* __restrict__ ninv,
                    float* __restrict__ out) {
    __shared__ __align__(16) float lds[2 * BUF_F];   // 16 KB

    const int lane = threadIdx.x;
    const int seg  = lane & 7;
    const size_t row = (size_t)blockIdx.x * 8 + (lane >> 3);
    const int c    = (int)(row & (C_DIM - 1));
    const int lk   = lane & 7;

    const int ds  = lane >> 3;
    const int du  = lane & 7;
    const int swz = du ^ ds;

    const float beta = beta_p[0];
    const float omb  = __fsub_rn(1.0f, beta);
    const float bnc  = bn[c];
    const float nic  = ninv[c];
    const float bc   = b[c];

    float mem = 0.0f;
    int   mask = 0;

    {
        int rel = ds * SEGL - WARM;
        if (rel < 0) rel = 0;
        const float* g = x + rel + 4 * swz;
        #pragma unroll
        for (int q = 0; q < 8; ++q) {
            const size_t grow = (size_t)(blockIdx.x * 8 + q);
            dma16(g + grow * T_DIM, lds + q * (8 * PW));
        }
    }

    #pragma unroll 1
    for (int P = 0; P < NPH; ++P) {
        const int cur = P & 1;
        float* buf = lds + cur * BUF_F;

        if (P + 1 < NPH) {
            int rel = ds * SEGL - WARM + (P + 1) * PW;
            if (rel < 0) rel = 0;
            const float* g = x + rel + 4 * swz;
            float* dst = lds + (cur ^ 1) * BUF_F;
            #pragma unroll
            for (int q = 0; q < 8; ++q) {
                const size_t grow = (size_t)(blockIdx.x * 8 + q);
                dma16(g + grow * T_DIM, dst + q * (8 * PW));
            }
        }

        if (P <= WARM_PH || P == NPH - 1) { WAITVM(8); } else { WAITVM(16); }

        float* my = buf + lane * PW;

        if (P < WARM_PH) {
            #pragma unroll
            for (int g = 0; g < PW / 4; ++g) {
                float4 v = *(const float4*)(my + 4 * (g ^ lk));
                STEP4_NOSTORE(v);
            }
            if (P == WARM_PH - 1) {
                if (seg == 0) { mem = 0.0f; mask = 0; }
            }
        } else {
            #pragma unroll
            for (int g = 0; g < PW / 4; ++g) {
                float4 v = *(const float4*)(my + 4 * (g ^ lk));
                float4 o;
                STEP4_STORE(v, o);
                *(float4*)(my + 4 * (g ^ lk)) = o;
            }
            __builtin_amdgcn_s_waitcnt(WAITCNT_LGKM0);

            const int rel = ds * SEGL - WARM + P * PW;
            #pragma unroll
            for (int q = 0; q < 8; ++q) {
                const size_t grow = (size_t)(blockIdx.x * 8 + q);
                float4 v = *(const float4*)(buf + (8 * q + ds) * PW + 4 * swz);
                *(float4*)(out + grow * T_DIM + rel + 4 * du) = v;
            }
        }
    }
}

extern "C" void kernel_launch(void* const* d_in, const int* in_sizes, int n_in,
                              void* d_out, int out_size, void* d_ws, size_t ws_size,
                              hipStream_t stream) {
    const float* x    = (const float*)d_in[0];
    const float* w    = (const float*)d_in[1];
    const float* beta = (const float*)d_in[2];
    const float* b    = (const float*)d_in[3];
    float* out  = (float*)d_out;
    float* bn   = (float*)d_ws;          // 256 floats
    float* ninv = bn + C_DIM;            // 256 floats

    norm_kernel<<<C_DIM, 64, 0, stream>>>(w, b, bn, ninv);

    if (ws_size >= 4096 + (size_t)PK_BYTES) {
        unsigned* pk = (unsigned*)((char*)d_ws + 4096);
        lif_pack_kernel<<<(NROWS * SEGS) / NSTR, NSTR, 0, stream>>>(x, beta, b, bn, ninv, pk);
        expand_kernel<<<NROWS / 8, NSTR, 0, stream>>>(pk, out);
    } else {
        lif_seg_kernel<<<(NROWS * SEGS) / NSTR, NSTR, 0, stream>>>(x, beta, b, bn, ninv, out);
    }
}